// Round 2
// baseline (211.281 us; speedup 1.0000x reference)
//
#include <hip/hip_runtime.h>
#include <math.h>

#define TAU_F 0.07f
#define B_ 2
#define CIN 64
#define H_ 128
#define W_ 256
#define CC 96      // COST_CH
#define G_ 8
#define CG 12
#define DP 32
#define HW_ (H_*W_)

// ---------------------------------------------------------------------------
// Kernel 1: transpose weights [96][64] -> [64][96] so the fused kernel's
// inner loop reads 48 contiguous floats per input channel (s_load path).
// ---------------------------------------------------------------------------
__global__ void wtrans_kernel(const float* __restrict__ WL,
                              const float* __restrict__ WR,
                              float* __restrict__ WtL,
                              float* __restrict__ WtR) {
    int i = blockIdx.x * 256 + threadIdx.x;       // 0 .. 2*6144-1
    if (i >= 2 * CIN * CC) return;
    int side = i / (CIN * CC);
    int r = i % (CIN * CC);
    int c = r / CC;
    int o = r % CC;
    const float* src = side ? WR : WL;
    float* dst = side ? WtR : WtL;
    dst[r] = src[o * CIN + c];                    // Wt[c][o] = W[o][c]
}

// ---------------------------------------------------------------------------
// Fused kernel: block = (b,h). 1024 threads.
//   half = t>>9 : which 48 channels (4 groups) this thread projects
//   side = (t&511)>>8, w = t&255
// Phase 1: projection y[48] per (side,w), L2-norm joined across halves (LDS).
// Phase 2 (two passes p=0,1): half==p threads write their 4 groups' planes to
// LDS; all threads compute sim for groups p*4..p*4+3 and stream output.
// Plane layout per side: S[(gq*3+j)*1024 + w*4 + e], ch = gq*12 + j*4 + e.
// ---------------------------------------------------------------------------
__global__ __launch_bounds__(1024, 4) void fused_kernel(
    const float* __restrict__ F_L, const float* __restrict__ F_R,
    const float* __restrict__ WtL, const float* __restrict__ WtR,
    float* __restrict__ out)
{
    __shared__ float Sfl[12288];   // 4 groups * 3 planes * 256 w * 4 ch = 48 KB
    __shared__ float Sfr[12288];   // 48 KB
    __shared__ float ssS[1024];
    __shared__ float psiS[DP];

    const int t = threadIdx.x;
    const int b = blockIdx.x >> 7;
    const int h = blockIdx.x & 127;
    const int half = t >> 9;        // wave-uniform
    const int idx  = t & 511;
    const int side = idx >> 8;      // wave-uniform
    const int w    = idx & 255;

    if (t < DP)
        psiS[t] = -sinf(6.28318530717958647692f * (float)t / (float)DP) / TAU_F;

    const float* F  = side ? F_R : F_L;
    const float* Wt = side ? WtR : WtL;

    // ---- Phase 1: projection -------------------------------------------
    float y[48];
#pragma unroll
    for (int k = 0; k < 48; ++k) y[k] = 0.f;

    const float* fp = F + (size_t)b * CIN * HW_ + h * W_ + w;
    for (int c = 0; c < CIN; ++c) {
        float f = fp[c * HW_];                    // coalesced 256B/wave
        const float* wr = Wt + c * CC + half * 48; // wave-uniform -> s_load
#pragma unroll
        for (int k = 0; k < 48; ++k) y[k] = fmaf(f, wr[k], y[k]);
    }

    float ss = 0.f;
#pragma unroll
    for (int k = 0; k < 48; ++k) ss = fmaf(y[k], y[k], ss);
    ssS[t] = ss;
    __syncthreads();
    float tot = ss + ssS[t ^ 512];
    float r = 1.0f / fmaxf(sqrtf(tot), 1e-12f);

    // ---- Phase 2: two group-passes -------------------------------------
    const int w2 = t & 255;
    const int gl = (t >> 8) & 3;
    const float A = -1.0f / (3.46410161513775459f * TAU_F); // -1/(sqrt(12)*tau)

#pragma unroll
    for (int p = 0; p < 2; ++p) {
        if (p) __syncthreads();      // pass-A sim reads done before overwrite
        if (half == p) {
            float* S = side ? Sfr : Sfl;
#pragma unroll
            for (int gq = 0; gq < 4; ++gq) {
#pragma unroll
                for (int j = 0; j < 3; ++j) {
                    float4 v;
                    v.x = y[gq*12 + j*4 + 0] * r;
                    v.y = y[gq*12 + j*4 + 1] * r;
                    v.z = y[gq*12 + j*4 + 2] * r;
                    v.w = y[gq*12 + j*4 + 3] * r;
                    *(float4*)&S[((gq*3 + j) * 256 + w) * 4] = v;
                }
            }
        }
        __syncthreads();

        // sim for groups g = p*4 + gl
        const float4 fl0 = *(const float4*)&Sfl[((gl*3 + 0) * 256 + w2) * 4];
        const float4 fl1 = *(const float4*)&Sfl[((gl*3 + 1) * 256 + w2) * 4];
        const float4 fl2 = *(const float4*)&Sfl[((gl*3 + 2) * 256 + w2) * 4];

        size_t ob = (((size_t)(b * G_ + p*4 + gl) * DP) * H_ + h) * (size_t)W_ + w2;
#pragma unroll
        for (int d = 0; d < DP; ++d) {
            int wd = w2 - d; if (wd < 0) wd = 0;
            float4 a0 = *(const float4*)&Sfr[((gl*3 + 0) * 256 + wd) * 4];
            float4 a1 = *(const float4*)&Sfr[((gl*3 + 1) * 256 + wd) * 4];
            float4 a2 = *(const float4*)&Sfr[((gl*3 + 2) * 256 + wd) * 4];
            float acc;
            acc = fl0.x * a0.x;
            acc = fmaf(fl0.y, a0.y, acc);
            acc = fmaf(fl0.z, a0.z, acc);
            acc = fmaf(fl0.w, a0.w, acc);
            acc = fmaf(fl1.x, a1.x, acc);
            acc = fmaf(fl1.y, a1.y, acc);
            acc = fmaf(fl1.z, a1.z, acc);
            acc = fmaf(fl1.w, a1.w, acc);
            acc = fmaf(fl2.x, a2.x, acc);
            acc = fmaf(fl2.y, a2.y, acc);
            acc = fmaf(fl2.z, a2.z, acc);
            acc = fmaf(fl2.w, a2.w, acc);
            out[ob + (size_t)d * HW_] = fmaf(acc, A, psiS[d]);
        }
    }
}

// ---------------------------------------------------------------------------
extern "C" void kernel_launch(void* const* d_in, const int* in_sizes, int n_in,
                              void* d_out, int out_size, void* d_ws, size_t ws_size,
                              hipStream_t stream) {
    const float* F_L = (const float*)d_in[0];
    const float* F_R = (const float*)d_in[1];
    const float* WL  = (const float*)d_in[2];
    const float* WR  = (const float*)d_in[3];
    float* out = (float*)d_out;
    float* ws  = (float*)d_ws;

    float* WtL = ws;
    float* WtR = ws + CIN * CC;

    wtrans_kernel<<<(2 * CIN * CC + 255) / 256, 256, 0, stream>>>(WL, WR, WtL, WtR);
    fused_kernel<<<B_ * H_, 1024, 0, stream>>>(F_L, F_R, WtL, WtR, out);
}

// Round 6
// 207.823 us; speedup vs baseline: 1.0166x; 1.0166x over previous
//
#include <hip/hip_runtime.h>
#include <math.h>

#define TAU_F 0.07f
#define B_ 2
#define CIN 64
#define H_ 128
#define W_ 256
#define CC 96      // COST_CH
#define G_ 8
#define CG 12
#define DP 32
#define HW_ (H_*W_)
#define ROWF (W_*CG)   // floats per (b,h,g) row in plane layout = 3072

// ---------------------------------------------------------------------------
// Kernel 1: transpose weights [96][64] -> [64][96] so the projection kernel's
// inner loop reads contiguous floats per input channel (s_load path).
// ---------------------------------------------------------------------------
__global__ void wtrans_kernel(const float* __restrict__ WL,
                              const float* __restrict__ WR,
                              float* __restrict__ WtL,
                              float* __restrict__ WtR) {
    int i = blockIdx.x * 256 + threadIdx.x;       // 0 .. 2*6144-1
    if (i >= 2 * CIN * CC) return;
    int side = i / (CIN * CC);
    int r = i % (CIN * CC);
    int c = r / CC;
    int o = r % CC;
    const float* src = side ? WR : WL;
    float* dst = side ? WtR : WtL;
    dst[r] = src[o * CIN + c];                    // Wt[c][o] = W[o][c]
}

// ---------------------------------------------------------------------------
// Kernel 2: projection + L2 norm, occupancy-fixed.
// 1024 blocks: blk -> (b, h, wh, side); 256 threads: t -> (half48, wl).
// Each thread projects 48 channels of pixel (b,h,wh*128+wl) of one side.
// F is staged through LDS in 16-channel chunks (keeps FETCH at 32 MB).
// Norm joined across the two halves via LDS pair-reduce.
// Output in plane layout per (b,h,g) row: base = ((b*H+h)*G+g)*3072,
// channel cg=4j+e of pixel w at base + j*1024 + w*4 + e.
// ---------------------------------------------------------------------------
__global__ __launch_bounds__(256, 4) void proj_kernel(
    const float* __restrict__ F_L, const float* __restrict__ F_R,
    const float* __restrict__ WtL, const float* __restrict__ WtR,
    float* __restrict__ outL, float* __restrict__ outR)
{
    __shared__ float Fstage[16 * 128];   // 8 KB
    __shared__ float ssS[256];

    const int blk  = blockIdx.x;
    const int side = blk & 1;
    const int wh   = (blk >> 1) & 1;
    const int h    = (blk >> 2) & 127;
    const int b    = blk >> 9;

    const int t    = threadIdx.x;
    const int half = t >> 7;             // 0/1 : channels half*48..
    const int wl   = t & 127;
    const int w    = wh * 128 + wl;

    const float* F  = side ? F_R : F_L;
    const float* Wt = side ? WtR : WtL;
    float* out      = side ? outR : outL;

    float y[48];
#pragma unroll
    for (int k = 0; k < 48; ++k) y[k] = 0.f;

    const float* fbase = F + (size_t)b * CIN * HW_ + h * W_ + wh * 128;

    // 4 chunks of 16 channels
    for (int cc = 0; cc < 4; ++cc) {
        // cooperative stage: 16 ch x 128 w = 2048 floats, 8 floats/thread
        {
            int ci  = t >> 4;            // 0..15
            int off = (t & 15) * 8;      // 0..120
            const float* src = fbase + (size_t)(cc * 16 + ci) * HW_ + off;
            *(float4*)&Fstage[ci * 128 + off]     = *(const float4*)&src[0];
            *(float4*)&Fstage[ci * 128 + off + 4] = *(const float4*)&src[4];
        }
        __syncthreads();
#pragma unroll
        for (int ci = 0; ci < 16; ++ci) {
            float f = Fstage[ci * 128 + wl];
            const float* wr = Wt + (cc * 16 + ci) * CC + half * 48;  // uniform
#pragma unroll
            for (int k = 0; k < 48; ++k) y[k] = fmaf(f, wr[k], y[k]);
        }
        __syncthreads();
    }

    float ss = 0.f;
#pragma unroll
    for (int k = 0; k < 48; ++k) ss = fmaf(y[k], y[k], ss);
    ssS[t] = ss;
    __syncthreads();
    float tot = ss + ssS[t ^ 128];
    float r = 1.0f / fmaxf(sqrtf(tot), 1e-12f);

    size_t base = (size_t)(b * H_ + h) * (G_ * ROWF);
#pragma unroll
    for (int gq = 0; gq < 4; ++gq) {
        int g = half * 4 + gq;
#pragma unroll
        for (int j = 0; j < 3; ++j) {
            float4 v;
            v.x = y[gq*12 + j*4 + 0] * r;
            v.y = y[gq*12 + j*4 + 1] * r;
            v.z = y[gq*12 + j*4 + 2] * r;
            v.w = y[gq*12 + j*4 + 3] * r;
            *(float4*)&out[base + (size_t)g * ROWF + j * (W_*4) + w * 4] = v;
        }
    }
}

// ---------------------------------------------------------------------------
// Kernel 3: shifted group-dot cost volume (round-1 verified structure).
// One block = one (b,g,h) row; FL/FR rows staged in LDS (24 KB -> 6 blk/CU).
// ---------------------------------------------------------------------------
__global__ __launch_bounds__(256) void sim_kernel(
    const float* __restrict__ PL, const float* __restrict__ PR,
    float* __restrict__ out)
{
    __shared__ float flS[ROWF];
    __shared__ float frS[ROWF];
    __shared__ float psiS[DP];

    int blk = blockIdx.x;
    int h = blk % H_;
    int g = (blk / H_) % G_;
    int b = blk / (H_ * G_);
    int tid = threadIdx.x;

    size_t base = ((size_t)(b * H_ + h) * G_ + g) * ROWF;

#pragma unroll
    for (int i = tid; i < ROWF / 4; i += 256) {
        *(float4*)&flS[i * 4] = *(const float4*)&PL[base + (size_t)i * 4];
        *(float4*)&frS[i * 4] = *(const float4*)&PR[base + (size_t)i * 4];
    }
    if (tid < DP)
        psiS[tid] = -sinf(6.28318530717958647692f * (float)tid / (float)DP) / TAU_F;
    __syncthreads();

    const int w = tid;
    float4 fl0 = *(const float4*)&flS[0*1024 + w*4];
    float4 fl1 = *(const float4*)&flS[1*1024 + w*4];
    float4 fl2 = *(const float4*)&flS[2*1024 + w*4];

    const float A = -1.0f / (3.46410161513775459f * TAU_F);  // -1/(sqrt(12)*tau)
    size_t ob = ((size_t)(b * G_ + g) * DP * H_ + h) * W_ + w;

#pragma unroll
    for (int d = 0; d < DP; ++d) {
        int wd = w - d; if (wd < 0) wd = 0;
        float4 a0 = *(const float4*)&frS[0*1024 + wd*4];
        float4 a1 = *(const float4*)&frS[1*1024 + wd*4];
        float4 a2 = *(const float4*)&frS[2*1024 + wd*4];
        float acc;
        acc = fl0.x * a0.x;
        acc = fmaf(fl0.y, a0.y, acc);
        acc = fmaf(fl0.z, a0.z, acc);
        acc = fmaf(fl0.w, a0.w, acc);
        acc = fmaf(fl1.x, a1.x, acc);
        acc = fmaf(fl1.y, a1.y, acc);
        acc = fmaf(fl1.z, a1.z, acc);
        acc = fmaf(fl1.w, a1.w, acc);
        acc = fmaf(fl2.x, a2.x, acc);
        acc = fmaf(fl2.y, a2.y, acc);
        acc = fmaf(fl2.z, a2.z, acc);
        acc = fmaf(fl2.w, a2.w, acc);
        out[ob + (size_t)d * HW_] = fmaf(acc, A, psiS[d]);   // coalesced dword
    }
}

// ---------------------------------------------------------------------------
extern "C" void kernel_launch(void* const* d_in, const int* in_sizes, int n_in,
                              void* d_out, int out_size, void* d_ws, size_t ws_size,
                              hipStream_t stream) {
    const float* F_L = (const float*)d_in[0];
    const float* F_R = (const float*)d_in[1];
    const float* WL  = (const float*)d_in[2];
    const float* WR  = (const float*)d_in[3];
    float* out = (float*)d_out;
    float* ws  = (float*)d_ws;

    const size_t PROJ = (size_t)B_ * H_ * G_ * ROWF;   // 6,291,456 floats
    float* PLp = ws;
    float* PRp = ws + PROJ;
    float* WtL = ws + 2 * PROJ;
    float* WtR = WtL + CIN * CC;
    // ws bytes needed: (2*6291456 + 2*6144)*4 ≈ 48.05 MiB

    wtrans_kernel<<<(2 * CIN * CC + 255) / 256, 256, 0, stream>>>(WL, WR, WtL, WtR);
    proj_kernel<<<dim3(B_ * H_ * 2 * 2), 256, 0, stream>>>(F_L, F_R, WtL, WtR, PLp, PRp);
    sim_kernel<<<B_ * G_ * H_, 256, 0, stream>>>(PLp, PRp, out);
}

// Round 12
// 131.880 us; speedup vs baseline: 1.6021x; 1.5759x over previous
//
#include <hip/hip_runtime.h>
#include <math.h>

#define TAU_F 0.07f
#define B_ 2
#define CIN 64
#define H_ 128
#define W_ 256
#define CC 96      // COST_CH
#define G_ 8
#define CG 12
#define DP 32
#define HW_ (H_*W_)
#define ROWF (W_*CG)   // floats per (b,h,g) row in plane layout = 3072

// ---------------------------------------------------------------------------
// Kernel 1: transpose weights [96][64] -> [64][96] so the projection kernel's
// inner loop reads 48 contiguous floats per input channel via s_load.
// ---------------------------------------------------------------------------
__global__ void wtrans_kernel(const float* __restrict__ WL,
                              const float* __restrict__ WR,
                              float* __restrict__ WtL,
                              float* __restrict__ WtR) {
    int i = blockIdx.x * 256 + threadIdx.x;       // 0 .. 2*6144-1
    if (i >= 2 * CIN * CC) return;
    int side = i / (CIN * CC);
    int r = i % (CIN * CC);
    int c = r / CC;
    int o = r % CC;
    const float* src = side ? WR : WL;
    float* dst = side ? WtR : WtL;
    dst[r] = src[o * CIN + c];                    // Wt[c][o] = W[o][c]
}

// ---------------------------------------------------------------------------
// Kernel 2: projection + L2 norm.
// 1024 blocks: blk -> (side, wh, h, b); 256 threads: t -> (half48, wl).
// Each thread projects 48 channels of pixel (b,h,wh*128+wl) of one side.
// KEY FIX vs round 6: weight base forced into an SGPR via readfirstlane
// (half is wave-uniform: waves are 64-thread contiguous, half = t>>7), so
// weight loads are s_loads from the scalar cache, not per-lane vector loads.
// F is read DIRECTLY from global (coalesced 256B/wave; L2/L3 absorb the
// 2x re-read across the two halves) — no LDS staging, no barriers in the
// main loop, no bank conflicts.
// Output plane layout per (b,h,g) row: base=((b*H+h)*G+g)*3072, channel
// cg=4j+e of pixel w at base + j*1024 + w*4 + e (contract verified by sim).
// ---------------------------------------------------------------------------
__global__ __launch_bounds__(256, 4) void proj_kernel(
    const float* __restrict__ F_L, const float* __restrict__ F_R,
    const float* __restrict__ WtL, const float* __restrict__ WtR,
    float* __restrict__ outL, float* __restrict__ outR)
{
    __shared__ float ssS[256];

    const int blk  = blockIdx.x;
    const int side = blk & 1;
    const int wh   = (blk >> 1) & 1;
    const int h    = (blk >> 2) & 127;
    const int b    = blk >> 9;

    const int t    = threadIdx.x;
    const int half = t >> 7;             // 0/1 : channels half*48.. (wave-uniform)
    const int wl   = t & 127;
    const int w    = wh * 128 + wl;

    const float* F  = side ? F_R : F_L;
    const float* Wt = side ? WtR : WtL;
    float* out      = side ? outR : outL;

    // Force the wave-uniform channel offset into an SGPR -> s_load weights.
    const int hoff = __builtin_amdgcn_readfirstlane(half * 48);
    const float* WtU = Wt + hoff;

    float y[48];
#pragma unroll
    for (int k = 0; k < 48; ++k) y[k] = 0.f;

    const float* fp = F + (size_t)b * CIN * HW_ + h * W_ + wh * 128 + wl;

#pragma unroll 4
    for (int c = 0; c < CIN; ++c) {
        float f = fp[c * HW_];                    // coalesced 256B/wave, L1/L2 hit for 2nd half
        const float* wr = WtU + c * CC;           // SGPR base -> s_load_dwordx*
#pragma unroll
        for (int k = 0; k < 48; ++k) y[k] = fmaf(f, wr[k], y[k]);
    }

    float ss = 0.f;
#pragma unroll
    for (int k = 0; k < 48; ++k) ss = fmaf(y[k], y[k], ss);
    ssS[t] = ss;
    __syncthreads();
    float tot = ss + ssS[t ^ 128];                // join the two 48-ch halves
    float r = 1.0f / fmaxf(sqrtf(tot), 1e-12f);

    size_t base = (size_t)(b * H_ + h) * (G_ * ROWF);
#pragma unroll
    for (int gq = 0; gq < 4; ++gq) {
        int g = half * 4 + gq;
#pragma unroll
        for (int j = 0; j < 3; ++j) {
            float4 v;
            v.x = y[gq*12 + j*4 + 0] * r;
            v.y = y[gq*12 + j*4 + 1] * r;
            v.z = y[gq*12 + j*4 + 2] * r;
            v.w = y[gq*12 + j*4 + 3] * r;
            // lanes stride 16B -> coalesced dwordx4
            *(float4*)&out[base + (size_t)g * ROWF + j * (W_*4) + w * 4] = v;
        }
    }
}

// ---------------------------------------------------------------------------
// Kernel 3: shifted group-dot cost volume (round-1 verified, 0 conflicts).
// One block = one (b,g,h) row; FL/FR rows staged in LDS (24 KB -> 6 blk/CU).
// ---------------------------------------------------------------------------
__global__ __launch_bounds__(256) void sim_kernel(
    const float* __restrict__ PL, const float* __restrict__ PR,
    float* __restrict__ out)
{
    __shared__ float flS[ROWF];
    __shared__ float frS[ROWF];
    __shared__ float psiS[DP];

    int blk = blockIdx.x;
    int h = blk % H_;
    int g = (blk / H_) % G_;
    int b = blk / (H_ * G_);
    int tid = threadIdx.x;

    size_t base = ((size_t)(b * H_ + h) * G_ + g) * ROWF;

#pragma unroll
    for (int i = tid; i < ROWF / 4; i += 256) {
        *(float4*)&flS[i * 4] = *(const float4*)&PL[base + (size_t)i * 4];
        *(float4*)&frS[i * 4] = *(const float4*)&PR[base + (size_t)i * 4];
    }
    if (tid < DP)
        psiS[tid] = -sinf(6.28318530717958647692f * (float)tid / (float)DP) / TAU_F;
    __syncthreads();

    const int w = tid;
    float4 fl0 = *(const float4*)&flS[0*1024 + w*4];
    float4 fl1 = *(const float4*)&flS[1*1024 + w*4];
    float4 fl2 = *(const float4*)&flS[2*1024 + w*4];

    const float A = -1.0f / (3.46410161513775459f * TAU_F);  // -1/(sqrt(12)*tau)
    size_t ob = ((size_t)(b * G_ + g) * DP * H_ + h) * W_ + w;

#pragma unroll
    for (int d = 0; d < DP; ++d) {
        int wd = w - d; if (wd < 0) wd = 0;
        float4 a0 = *(const float4*)&frS[0*1024 + wd*4];
        float4 a1 = *(const float4*)&frS[1*1024 + wd*4];
        float4 a2 = *(const float4*)&frS[2*1024 + wd*4];
        float acc;
        acc = fl0.x * a0.x;
        acc = fmaf(fl0.y, a0.y, acc);
        acc = fmaf(fl0.z, a0.z, acc);
        acc = fmaf(fl0.w, a0.w, acc);
        acc = fmaf(fl1.x, a1.x, acc);
        acc = fmaf(fl1.y, a1.y, acc);
        acc = fmaf(fl1.z, a1.z, acc);
        acc = fmaf(fl1.w, a1.w, acc);
        acc = fmaf(fl2.x, a2.x, acc);
        acc = fmaf(fl2.y, a2.y, acc);
        acc = fmaf(fl2.z, a2.z, acc);
        acc = fmaf(fl2.w, a2.w, acc);
        out[ob + (size_t)d * HW_] = fmaf(acc, A, psiS[d]);   // coalesced dword
    }
}

// ---------------------------------------------------------------------------
extern "C" void kernel_launch(void* const* d_in, const int* in_sizes, int n_in,
                              void* d_out, int out_size, void* d_ws, size_t ws_size,
                              hipStream_t stream) {
    const float* F_L = (const float*)d_in[0];
    const float* F_R = (const float*)d_in[1];
    const float* WL  = (const float*)d_in[2];
    const float* WR  = (const float*)d_in[3];
    float* out = (float*)d_out;
    float* ws  = (float*)d_ws;

    const size_t PROJ = (size_t)B_ * H_ * G_ * ROWF;   // 6,291,456 floats
    float* PLp = ws;
    float* PRp = ws + PROJ;
    float* WtL = ws + 2 * PROJ;
    float* WtR = WtL + CIN * CC;
    // ws bytes needed: (2*6291456 + 2*6144)*4 ≈ 48.05 MiB

    wtrans_kernel<<<(2 * CIN * CC + 255) / 256, 256, 0, stream>>>(WL, WR, WtL, WtR);
    proj_kernel<<<dim3(B_ * H_ * 2 * 2), 256, 0, stream>>>(F_L, F_R, WtL, WtR, PLp, PRp);
    sim_kernel<<<B_ * G_ * H_, 256, 0, stream>>>(PLp, PRp, out);
}